// Round 1
// baseline (224.663 us; speedup 1.0000x reference)
//
#include <hip/hip_runtime.h>

// MADPSNet: per-agent expert-selected MLP chain.
// Key insight: reference computes all E experts then gathers one per agent;
// we compute ONLY the selected expert per agent (8x less work).
//
// Layer shapes (per agent, M=B=2048):
//  L1: [2048,256] @ Ws1[e][256,512] + bs1, relu -> h
//  L2: [2048,512] @ Ws2[e][512,256] + bs2, relu -> sh
//  L3: [2048,256] @ Wd1[e][256,512] + bd1, relu -> d
//  L4: [2048,512] @ Wd2[e][512,128] + bd2       -> out

#define BM 64
#define BN 64
#define BK 16

__global__ __launch_bounds__(256)
void moe_gemm_bias_act(const float* __restrict__ X, long long xAgentStride,
                       const float* __restrict__ W, long long wExpertStride,
                       const float* __restrict__ bias, int biasExpertStride,
                       const int* __restrict__ sel,
                       float* __restrict__ Y, long long yAgentStride,
                       int K, int N, int doRelu)
{
    const int agent = blockIdx.z;
    const long long e = (long long)sel[agent];
    const float* Xa = X + (long long)agent * xAgentStride;
    const float* We = W + e * wExpertStride;
    const float* be = bias + e * (long long)biasExpertStride;
    float*       Ya = Y + (long long)agent * yAgentStride;

    const int rowBase = blockIdx.y * BM;
    const int colBase = blockIdx.x * BN;

    __shared__ float As[BK][BM];
    __shared__ float Bs[BK][BN];

    const int tid = threadIdx.x;
    const int tr = tid / 16;          // 0..15 (output row group)
    const int tc = tid % 16;          // 0..15 (output col group)

    // loader indices
    const int aRow = tid / 4;         // 0..63
    const int aCol = (tid % 4) * 4;   // 0,4,8,12
    const int bRow = tid / 16;        // 0..15
    const int bCol = (tid % 16) * 4;  // 0..60

    float acc[4][4] = {};

    for (int k0 = 0; k0 < K; k0 += BK) {
        // A tile: As[k][m] = Xa[rowBase+aRow][k0+aCol+j]   (coalesced float4 read)
        float4 av = *reinterpret_cast<const float4*>(
            &Xa[(long long)(rowBase + aRow) * K + k0 + aCol]);
        As[aCol + 0][aRow] = av.x;
        As[aCol + 1][aRow] = av.y;
        As[aCol + 2][aRow] = av.z;
        As[aCol + 3][aRow] = av.w;
        // B tile: Bs[k][n] = We[k0+bRow][colBase+bCol+j]   (coalesced float4 read)
        float4 bv = *reinterpret_cast<const float4*>(
            &We[(long long)(k0 + bRow) * N + colBase + bCol]);
        *reinterpret_cast<float4*>(&Bs[bRow][bCol]) = bv;
        __syncthreads();

        #pragma unroll
        for (int k = 0; k < BK; ++k) {
            float ra[4], rb[4];
            *reinterpret_cast<float4*>(ra) =
                *reinterpret_cast<const float4*>(&As[k][tr * 4]);
            *reinterpret_cast<float4*>(rb) =
                *reinterpret_cast<const float4*>(&Bs[k][tc * 4]);
            #pragma unroll
            for (int i = 0; i < 4; ++i)
                #pragma unroll
                for (int j = 0; j < 4; ++j)
                    acc[i][j] = fmaf(ra[i], rb[j], acc[i][j]);
        }
        __syncthreads();
    }

    // epilogue: bias (+ relu), coalesced float4 store
    #pragma unroll
    for (int i = 0; i < 4; ++i) {
        const int row = rowBase + tr * 4 + i;
        float o[4];
        #pragma unroll
        for (int j = 0; j < 4; ++j) {
            float v = acc[i][j] + be[colBase + tc * 4 + j];
            if (doRelu) v = fmaxf(v, 0.0f);
            o[j] = v;
        }
        *reinterpret_cast<float4*>(&Ya[(long long)row * N + colBase + tc * 4]) =
            *reinterpret_cast<float4*>(o);
    }
}

extern "C" void kernel_launch(void* const* d_in, const int* in_sizes, int n_in,
                              void* d_out, int out_size, void* d_ws, size_t ws_size,
                              hipStream_t stream)
{
    constexpr int A = 8, B = 2048, S = 256;
    constexpr int H1 = 512, H2 = 256;
    constexpr int D1 = 512, D2 = 128;

    const float* inputs = (const float*)d_in[0];
    const int*   sel_s  = (const int*)d_in[1];   // laac_shallow [1,A]
    const int*   sel_d  = (const int*)d_in[2];   // laac_deep    [1,A]
    const float* Ws1 = (const float*)d_in[3];
    const float* bs1 = (const float*)d_in[4];
    const float* Ws2 = (const float*)d_in[5];
    const float* bs2 = (const float*)d_in[6];
    const float* Wd1 = (const float*)d_in[7];
    const float* bd1 = (const float*)d_in[8];
    const float* Wd2 = (const float*)d_in[9];
    const float* bd2 = (const float*)d_in[10];
    float* out = (float*)d_out;

    // workspace: h/d share buf0 (A*B*512 floats), sh in buf1 (A*B*256 floats)
    float* buf0 = (float*)d_ws;                       // [A,B,512]
    float* buf1 = buf0 + (size_t)A * B * H1;          // [A,B,256]

    dim3 block(256);

    // L1: inputs[A,B,S] @ Ws1[e][S,H1] + bs1, relu -> buf0 [A,B,H1]
    {
        dim3 grid(H1 / BN, B / BM, A);
        moe_gemm_bias_act<<<grid, block, 0, stream>>>(
            inputs, (long long)B * S, Ws1, (long long)S * H1, bs1, H1,
            sel_s, buf0, (long long)B * H1, S, H1, 1);
    }
    // L2: buf0[A,B,H1] @ Ws2[e][H1,H2] + bs2, relu -> buf1 [A,B,H2]
    {
        dim3 grid(H2 / BN, B / BM, A);
        moe_gemm_bias_act<<<grid, block, 0, stream>>>(
            buf0, (long long)B * H1, Ws2, (long long)H1 * H2, bs2, H2,
            sel_s, buf1, (long long)B * H2, H1, H2, 1);
    }
    // L3: buf1[A,B,H2] @ Wd1[e][H2,D1] + bd1, relu -> buf0 [A,B,D1]
    {
        dim3 grid(D1 / BN, B / BM, A);
        moe_gemm_bias_act<<<grid, block, 0, stream>>>(
            buf1, (long long)B * H2, Wd1, (long long)H2 * D1, bd1, D1,
            sel_d, buf0, (long long)B * D1, H2, D1, 1);
    }
    // L4: buf0[A,B,D1] @ Wd2[e][D1,D2] + bd2 -> out [A,B,D2]
    {
        dim3 grid(D2 / BN, B / BM, A);
        moe_gemm_bias_act<<<grid, block, 0, stream>>>(
            buf0, (long long)B * D1, Wd2, (long long)D1 * D2, bd2, D2,
            sel_d, out, (long long)B * D2, D1, D2, 0);
    }
}

// Round 2
// 71.126 us; speedup vs baseline: 3.1587x; 3.1587x over previous
//
#include <hip/hip_runtime.h>
#include <hip/hip_bf16.h>

// MADPSNet: per-agent expert-selected MLP chain, bf16 MFMA version.
// Only the selected expert per agent is computed (8x less work than ref).
//
// Pipeline (per call):
//  cast:  X fp32 -> bf16 (same layout)
//  4x transpose-cast: W[E][K][N] fp32 -> Wt[E][N][K] bf16  (B^T for contiguous K frags)
//  L1: Xb  [2048,256] @ W1t[e] -> relu -> act0 bf16 [2048,512]
//  L2: act0[2048,512] @ W2t[e] -> relu -> act1 bf16 [2048,256]
//  L3: act1[2048,256] @ W3t[e] -> relu -> act0 bf16 [2048,512]
//  L4: act0[2048,512] @ W4t[e] -> +bias -> out fp32 [2048,128]
//
// GEMM: m97 structure. 128x128 tile, BK=64, 256 thr = 4 waves (2x2), each wave
// 64x64 = 4x4 frags of mfma_f32_16x16x32_bf16, fp32 acc. global_load_lds
// width=16 staging, XOR chunk swizzle (linear LDS dest + inverse-swizzled
// global source + swizzled ds_read) -> conflict-free-ish LDS reads.

typedef __attribute__((ext_vector_type(8))) short bf16x8;
typedef __attribute__((ext_vector_type(4))) float f32x4;

__device__ __forceinline__ ushort f2b(float x) {
    __hip_bfloat16 h = __float2bfloat16(x);
    return *reinterpret_cast<ushort*>(&h);
}

#define GLOAD_LDS(g, l)                                                     \
    __builtin_amdgcn_global_load_lds(                                       \
        (const __attribute__((address_space(1))) void*)(g),                 \
        (__attribute__((address_space(3))) void*)(l), 16, 0, 0)

// ---------------------------------------------------------------- casts ---
__global__ __launch_bounds__(256)
void cast_f32_bf16(const float* __restrict__ in, ushort* __restrict__ out, int n4)
{
    int i = blockIdx.x * blockDim.x + threadIdx.x;
    const int stride = gridDim.x * blockDim.x;
    for (; i < n4; i += stride) {
        float4 v = reinterpret_cast<const float4*>(in)[i];
        ushort4 o;
        o.x = f2b(v.x); o.y = f2b(v.y); o.z = f2b(v.z); o.w = f2b(v.w);
        reinterpret_cast<ushort4*>(out)[i] = o;
    }
}

// W[e][K][N] fp32 -> Wt[e][N][K] bf16, 32x32 LDS tiles
__global__ __launch_bounds__(256)
void transpose_cast_w(const float* __restrict__ W, ushort* __restrict__ Wt,
                      int K, int N)
{
    const int e = blockIdx.z;
    W  += (size_t)e * K * N;
    Wt += (size_t)e * K * N;
    __shared__ float t[32][33];
    const int tx = threadIdx.x;   // 0..31
    const int ty = threadIdx.y;   // 0..7
    const int n0 = blockIdx.x * 32;
    const int k0 = blockIdx.y * 32;
    #pragma unroll
    for (int j = 0; j < 4; ++j)
        t[ty + j * 8][tx] = W[(size_t)(k0 + ty + j * 8) * N + n0 + tx];
    __syncthreads();
    #pragma unroll
    for (int j = 0; j < 4; ++j) {
        const int n = ty + j * 8;
        Wt[(size_t)(n0 + n) * K + k0 + tx] = f2b(t[tx][n]);
    }
}

// ----------------------------------------------------------------- GEMM ---
// A: bf16 [agent][M][K] (row-major), Bt: bf16 [E][N][K], bias fp32 [E][N]
template<int RELU, int OUTF32>
__global__ __launch_bounds__(256)
void gemm_moe(const ushort* __restrict__ A, long long aStride,
              const ushort* __restrict__ Bt,
              const float* __restrict__ bias,
              const int* __restrict__ sel,
              void* __restrict__ Yv, long long yStride,
              int N, int K)
{
    const int agent = blockIdx.z;
    const long long e = (long long)sel[agent];
    const ushort* __restrict__ Aa = A + (long long)agent * aStride;
    const ushort* __restrict__ Be = Bt + e * (long long)N * K;
    const float*  __restrict__ be = bias + e * (long long)N;

    const int rowBase = blockIdx.y * 128;
    const int colBase = blockIdx.x * 128;

    __shared__ __align__(16) ushort lds[2 * 128 * 64];   // 32 KB: A tile | B tile
    ushort* sA = lds;
    ushort* sB = lds + 128 * 64;

    const int tid  = threadIdx.x;
    const int lane = tid & 63;
    const int wid  = tid >> 6;
    const int wr   = wid >> 1;          // wave row (0..1)
    const int wc   = wid & 1;           // wave col (0..1)
    const int r15  = lane & 15;
    const int lh   = lane >> 4;         // 0..3

    // staging: per issue i (0..3): row = i*32 + srow, physical chunk = tid%8,
    // global source chunk = (tid%8) ^ (row&7)  (row&7 == srow&7)
    const int srow = tid >> 3;                  // 0..31
    const int schk = (tid & 7) ^ (srow & 7);    // pre-swizzled source chunk

    f32x4 acc[4][4] = {};

    const int ldsWaveElem = wid * 512;          // wid*1024 bytes

    for (int k0 = 0; k0 < K; k0 += 64) {
        #pragma unroll
        for (int i = 0; i < 4; ++i) {
            const ushort* ga = &Aa[(long long)(rowBase + i * 32 + srow) * K + k0 + schk * 8];
            GLOAD_LDS(ga, &sA[i * 2048 + ldsWaveElem]);
            const ushort* gb = &Be[(long long)(colBase + i * 32 + srow) * K + k0 + schk * 8];
            GLOAD_LDS(gb, &sB[i * 2048 + ldsWaveElem]);
        }
        __syncthreads();   // compiler drains vmcnt(0) before s_barrier

        #pragma unroll
        for (int ks = 0; ks < 2; ++ks) {
            bf16x8 af[4], bfr[4];
            #pragma unroll
            for (int m = 0; m < 4; ++m) {
                const int row = wr * 64 + m * 16 + r15;
                const int ch  = (ks * 4 + lh) ^ (row & 7);
                af[m] = *reinterpret_cast<const bf16x8*>(&sA[row * 64 + ch * 8]);
            }
            #pragma unroll
            for (int n = 0; n < 4; ++n) {
                const int row = wc * 64 + n * 16 + r15;
                const int ch  = (ks * 4 + lh) ^ (row & 7);
                bfr[n] = *reinterpret_cast<const bf16x8*>(&sB[row * 64 + ch * 8]);
            }
            #pragma unroll
            for (int m = 0; m < 4; ++m)
                #pragma unroll
                for (int n = 0; n < 4; ++n)
                    acc[m][n] = __builtin_amdgcn_mfma_f32_16x16x32_bf16(
                        af[m], bfr[n], acc[m][n], 0, 0, 0);
        }
        __syncthreads();
    }

    // ------------------------------------------------------------ epilogue
    if (OUTF32) {
        float* Ya = (float*)Yv + (long long)agent * yStride;
        #pragma unroll
        for (int n = 0; n < 4; ++n) {
            const int col = wc * 64 + n * 16 + r15;
            const float bv = be[colBase + col];
            #pragma unroll
            for (int m = 0; m < 4; ++m) {
                #pragma unroll
                for (int j = 0; j < 4; ++j) {
                    const int row = wr * 64 + m * 16 + lh * 4 + j;
                    float v = acc[m][n][j] + bv;
                    if (RELU) v = fmaxf(v, 0.0f);
                    Ya[(long long)(rowBase + row) * N + colBase + col] = v;
                }
            }
        }
    } else {
        // stage C tile (128x128 bf16 = 32 KB) through LDS for coalesced stores
        ushort* sC = lds;
        #pragma unroll
        for (int n = 0; n < 4; ++n) {
            const int col = wc * 64 + n * 16 + r15;
            const float bv = be[colBase + col];
            #pragma unroll
            for (int m = 0; m < 4; ++m) {
                #pragma unroll
                for (int j = 0; j < 4; ++j) {
                    const int row = wr * 64 + m * 16 + lh * 4 + j;
                    float v = acc[m][n][j] + bv;
                    if (RELU) v = fmaxf(v, 0.0f);
                    sC[row * 128 + col] = f2b(v);
                }
            }
        }
        __syncthreads();
        ushort* Ya = (ushort*)Yv + (long long)agent * yStride;
        #pragma unroll
        for (int i = 0; i < 8; ++i) {
            const int idx = (i * 256 + tid) * 8;
            const int row = idx >> 7;
            const int col = idx & 127;
            *reinterpret_cast<bf16x8*>(&Ya[(long long)(rowBase + row) * N + colBase + col]) =
                *reinterpret_cast<const bf16x8*>(&sC[idx]);
        }
    }
}

// --------------------------------------------------------------- launch ---
extern "C" void kernel_launch(void* const* d_in, const int* in_sizes, int n_in,
                              void* d_out, int out_size, void* d_ws, size_t ws_size,
                              hipStream_t stream)
{
    constexpr int A = 8, B = 2048, S = 256;
    constexpr int E = 8;
    constexpr int H1 = 512, H2 = 256;
    constexpr int D1 = 512, D2 = 128;

    const float* inputs = (const float*)d_in[0];
    const int*   sel_s  = (const int*)d_in[1];
    const int*   sel_d  = (const int*)d_in[2];
    const float* Ws1 = (const float*)d_in[3];
    const float* bs1 = (const float*)d_in[4];
    const float* Ws2 = (const float*)d_in[5];
    const float* bs2 = (const float*)d_in[6];
    const float* Wd1 = (const float*)d_in[7];
    const float* bd1 = (const float*)d_in[8];
    const float* Wd2 = (const float*)d_in[9];
    const float* bd2 = (const float*)d_in[10];
    float* out = (float*)d_out;

    // workspace layout (bf16 elements)
    ushort* Xb   = (ushort*)d_ws;                    // [A][B][S]
    ushort* W1t  = Xb   + (size_t)A * B * S;         // [E][H1][S]
    ushort* W2t  = W1t  + (size_t)E * S * H1;        // [E][H2][H1]
    ushort* W3t  = W2t  + (size_t)E * H1 * H2;       // [E][D1][H2]
    ushort* W4t  = W3t  + (size_t)E * H2 * D1;       // [E][D2][D1]
    ushort* act0 = W4t  + (size_t)E * D1 * D2;       // [A][B][H1] (h, then d)
    ushort* act1 = act0 + (size_t)A * B * H1;        // [A][B][H2] (sh)

    cast_f32_bf16<<<1024, 256, 0, stream>>>(inputs, Xb, (A * B * S) / 4);
    transpose_cast_w<<<dim3(H1 / 32, S  / 32, E), dim3(32, 8), 0, stream>>>(Ws1, W1t, S,  H1);
    transpose_cast_w<<<dim3(H2 / 32, H1 / 32, E), dim3(32, 8), 0, stream>>>(Ws2, W2t, H1, H2);
    transpose_cast_w<<<dim3(D1 / 32, H2 / 32, E), dim3(32, 8), 0, stream>>>(Wd1, W3t, H2, D1);
    transpose_cast_w<<<dim3(D2 / 32, D1 / 32, E), dim3(32, 8), 0, stream>>>(Wd2, W4t, D1, D2);

    // L1: Xb @ W1t -> relu -> act0
    gemm_moe<1, 0><<<dim3(H1 / 128, B / 128, A), 256, 0, stream>>>(
        Xb, (long long)B * S, W1t, bs1, sel_s, act0, (long long)B * H1, H1, S);
    // L2: act0 @ W2t -> relu -> act1
    gemm_moe<1, 0><<<dim3(H2 / 128, B / 128, A), 256, 0, stream>>>(
        act0, (long long)B * H1, W2t, bs2, sel_s, act1, (long long)B * H2, H2, H1);
    // L3: act1 @ W3t -> relu -> act0
    gemm_moe<1, 0><<<dim3(D1 / 128, B / 128, A), 256, 0, stream>>>(
        act1, (long long)B * H2, W3t, bd1, sel_d, act0, (long long)B * D1, D1, H2);
    // L4: act0 @ W4t -> out (fp32, no relu)
    gemm_moe<0, 1><<<dim3(D2 / 128, B / 128, A), 256, 0, stream>>>(
        act0, (long long)B * D1, W4t, bd2, sel_d, (void*)out, (long long)B * D2, D2, D1);
}

// Round 3
// 52.836 us; speedup vs baseline: 4.2520x; 1.3461x over previous
//
#include <hip/hip_runtime.h>
#include <hip/hip_bf16.h>

// MADPSNet fused: entire 4-layer expert-selected MLP in ONE kernel.
//  - 256 blocks (8 agents x 32 row-blocks of 64 rows), 256 thr = 4 waves, 1 block/CU
//  - activations never touch HBM: X->h->sh->d all in LDS (96 KB, lifetime-reused)
//  - weights stream from L2 as per-lane MFMA B-fragments (no LDS staging, no
//    per-K-step barriers; only one barrier per layer boundary)
//  - agent = bid%8 -> each XCD's L2 caches exactly one agent's weights
//  - LDS act buffers XOR-swizzled (write+read both swizzled) -> ~2-way banks
// Prep: one kernel transposes+casts all 4 weight tensors to bf16 [E][N][K].

typedef __attribute__((ext_vector_type(8))) short bf16x8;
typedef __attribute__((ext_vector_type(4))) float f32x4;

__device__ __forceinline__ ushort f2b(float x) {
    __hip_bfloat16 h = __float2bfloat16(x);
    return *reinterpret_cast<ushort*>(&h);
}

// swizzled LDS byte offset for bf16 element (row, col); row stride = K elems.
// 16B-chunk XOR with row&7 -> 16 rows reading the same column hit 8 distinct
// 16B slots (2-way = free, m136).
__device__ __forceinline__ int swz_off(int row, int col, int K) {
    const int chunk = col >> 3;
    const int phys  = chunk ^ (row & 7);
    return row * (K * 2) + (phys << 4) + ((col & 7) << 1);
}

// ------------------------------------------------------------------ prep ---
// W[e][K][N] fp32 -> Wt[e][N][K] bf16 for all 4 layers, one kernel.
__global__ __launch_bounds__(256)
void prep_weights(const float* __restrict__ Ws1, const float* __restrict__ Ws2,
                  const float* __restrict__ Wd1, const float* __restrict__ Wd2,
                  ushort* __restrict__ W1t, ushort* __restrict__ W2t,
                  ushort* __restrict__ W3t, ushort* __restrict__ W4t)
{
    int t = blockIdx.x;
    const int e = blockIdx.z;
    const float* W; ushort* Wt; int K, N;
    if (t < 128)      { W = Ws1; Wt = W1t; K = 256; N = 512; }
    else if (t < 256) { t -= 128; W = Ws2; Wt = W2t; K = 512; N = 256; }
    else if (t < 384) { t -= 256; W = Wd1; Wt = W3t; K = 256; N = 512; }
    else              { t -= 384; W = Wd2; Wt = W4t; K = 512; N = 128; }
    W  += (size_t)e * K * N;
    Wt += (size_t)e * K * N;
    const int tn = N / 32;
    const int n0 = (t % tn) * 32;
    const int k0 = (t / tn) * 32;

    __shared__ float tile[32][33];
    const int tx = threadIdx.x;   // 0..31
    const int ty = threadIdx.y;   // 0..7
    #pragma unroll
    for (int j = 0; j < 4; ++j)
        tile[ty + j * 8][tx] = W[(size_t)(k0 + ty + j * 8) * N + n0 + tx];
    __syncthreads();
    #pragma unroll
    for (int j = 0; j < 4; ++j) {
        const int n = ty + j * 8;
        Wt[(size_t)(n0 + n) * K + k0 + tx] = f2b(tile[tx][n]);
    }
}

// ----------------------------------------------------------- fused layer ---
// A: LDS [64][K] bf16 swizzled. B: global Wt [N][K] bf16 (expert-selected).
// Out: LDS [64][N] swizzled (+relu) OR global fp32 [64][N].
template<int K, int N, int RELU>
__device__ __forceinline__ void layer_mlp(
    const ushort* __restrict__ Wt, const float* __restrict__ bias,
    const ushort* __restrict__ sIn, ushort* __restrict__ sOut,
    float* __restrict__ gOut, int wid, int lane)
{
    constexpr int F = N / 64;            // frag-cols per wave (waves split N 1x4)
    const int r15 = lane & 15, lh = lane >> 4;
    const int wcol = wid * (N / 4);

    f32x4 acc[4][F];
    #pragma unroll
    for (int m = 0; m < 4; ++m)
        #pragma unroll
        for (int f = 0; f < F; ++f)
            acc[m][f] = (f32x4){0.f, 0.f, 0.f, 0.f};

    #pragma unroll
    for (int k0 = 0; k0 < K; k0 += 32) {
        bf16x8 a[4];
        #pragma unroll
        for (int m = 0; m < 4; ++m) {
            const int row  = m * 16 + r15;
            const int phys = ((k0 >> 3) + lh) ^ (row & 7);
            a[m] = *reinterpret_cast<const bf16x8*>(
                reinterpret_cast<const char*>(sIn) + row * (K * 2) + (phys << 4));
        }
        bf16x8 b[F];
        #pragma unroll
        for (int f = 0; f < F; ++f) {
            const int col = wcol + f * 16 + r15;
            b[f] = *reinterpret_cast<const bf16x8*>(&Wt[(size_t)col * K + k0 + lh * 8]);
        }
        #pragma unroll
        for (int m = 0; m < 4; ++m)
            #pragma unroll
            for (int f = 0; f < F; ++f)
                acc[m][f] = __builtin_amdgcn_mfma_f32_16x16x32_bf16(
                    a[m], b[f], acc[m][f], 0, 0, 0);
    }

    #pragma unroll
    for (int f = 0; f < F; ++f) {
        const int col = wcol + f * 16 + r15;
        const float bv = bias[col];
        #pragma unroll
        for (int m = 0; m < 4; ++m) {
            #pragma unroll
            for (int j = 0; j < 4; ++j) {
                const int row = m * 16 + lh * 4 + j;   // C/D layout (m89)
                float v = acc[m][f][j] + bv;
                if (RELU) v = fmaxf(v, 0.f);
                if (gOut) {
                    gOut[(size_t)row * N + col] = v;
                } else {
                    *reinterpret_cast<ushort*>(
                        reinterpret_cast<char*>(sOut) + swz_off(row, col, N)) = f2b(v);
                }
            }
        }
    }
}

// ----------------------------------------------------------- fused kernel ---
__global__ __launch_bounds__(256, 1)
void madps_fused(const float* __restrict__ X,
                 const int* __restrict__ sel_s, const int* __restrict__ sel_d,
                 const ushort* __restrict__ W1t, const ushort* __restrict__ W2t,
                 const ushort* __restrict__ W3t, const ushort* __restrict__ W4t,
                 const float* __restrict__ bs1, const float* __restrict__ bs2,
                 const float* __restrict__ bd1, const float* __restrict__ bd2,
                 float* __restrict__ out)
{
    constexpr int S = 256, H1 = 512, H2 = 256, D1 = 512, D2 = 128;

    __shared__ __align__(16) ushort buf0[64 * 256];   // 32 KB: X, then sh
    __shared__ __align__(16) ushort buf1[64 * 512];   // 64 KB: h, then d

    const int bid   = blockIdx.x;
    const int agent = bid & 7;          // agent == XCD -> weights L2-resident
    const int rb    = bid >> 3;         // row-block within agent (0..31)
    const int tid   = threadIdx.x;
    const int lane  = tid & 63;
    const int wid   = tid >> 6;

    const long long es = sel_s[agent];
    const long long ed = sel_d[agent];

    const float* Xa = X + ((size_t)agent * 2048 + (size_t)rb * 64) * S;

    // ---- stage X [64][256] fp32 -> buf0 bf16 (swizzled) ----
    #pragma unroll
    for (int i = 0; i < 16; ++i) {
        const int flat4 = i * 256 + tid;        // float4 index, 64/row
        const int row = flat4 >> 6;
        const int c4  = flat4 & 63;
        const float4 v = reinterpret_cast<const float4*>(Xa)[flat4];
        ushort4 o;
        o.x = f2b(v.x); o.y = f2b(v.y); o.z = f2b(v.z); o.w = f2b(v.w);
        const int byteoff = (((c4 >> 1) ^ (row & 7)) << 4) | ((c4 & 1) << 3);
        *reinterpret_cast<ushort4*>(
            reinterpret_cast<char*>(buf0) + row * 512 + byteoff) = o;
    }
    __syncthreads();

    // L1: X(buf0, K=256) @ W1t -> relu -> h(buf1, N=512)
    layer_mlp<S, H1, 1>(W1t + es * (S * H1), bs1 + es * H1,
                        buf0, buf1, nullptr, wid, lane);
    __syncthreads();
    // L2: h(buf1, K=512) @ W2t -> relu -> sh(buf0, N=256)
    layer_mlp<H1, H2, 1>(W2t + es * (H1 * H2), bs2 + es * H2,
                         buf1, buf0, nullptr, wid, lane);
    __syncthreads();
    // L3: sh(buf0, K=256) @ W3t -> relu -> d(buf1, N=512)
    layer_mlp<H2, D1, 1>(W3t + ed * (H2 * D1), bd1 + ed * D1,
                         buf0, buf1, nullptr, wid, lane);
    __syncthreads();
    // L4: d(buf1, K=512) @ W4t + bias -> out fp32 [64][128]
    float* outP = out + ((size_t)agent * 2048 + (size_t)rb * 64) * D2;
    layer_mlp<D1, D2, 0>(W4t + ed * (D1 * D2), bd2 + ed * D2,
                         buf1, nullptr, outP, wid, lane);
}

// --------------------------------------------------------------- launch ---
extern "C" void kernel_launch(void* const* d_in, const int* in_sizes, int n_in,
                              void* d_out, int out_size, void* d_ws, size_t ws_size,
                              hipStream_t stream)
{
    constexpr int E = 8, S = 256, H1 = 512, H2 = 256, D1 = 512, D2 = 128;

    const float* inputs = (const float*)d_in[0];
    const int*   sel_s  = (const int*)d_in[1];
    const int*   sel_d  = (const int*)d_in[2];
    const float* Ws1 = (const float*)d_in[3];
    const float* bs1 = (const float*)d_in[4];
    const float* Ws2 = (const float*)d_in[5];
    const float* bs2 = (const float*)d_in[6];
    const float* Wd1 = (const float*)d_in[7];
    const float* bd1 = (const float*)d_in[8];
    const float* Wd2 = (const float*)d_in[9];
    const float* bd2 = (const float*)d_in[10];
    float* out = (float*)d_out;

    // workspace: transposed bf16 weights only
    ushort* W1t = (ushort*)d_ws;                     // [E][H1][S]
    ushort* W2t = W1t + (size_t)E * S * H1;          // [E][H2][H1]
    ushort* W3t = W2t + (size_t)E * H1 * H2;         // [E][D1][H2]
    ushort* W4t = W3t + (size_t)E * H2 * D1;         // [E][D2][D1]

    // 448 transpose tiles (128+128+128+64) x 8 experts, one kernel
    prep_weights<<<dim3(448, 1, E), dim3(32, 8), 0, stream>>>(
        Ws1, Ws2, Wd1, Wd2, W1t, W2t, W3t, W4t);

    madps_fused<<<dim3(256), dim3(256), 0, stream>>>(
        inputs, sel_s, sel_d, W1t, W2t, W3t, W4t,
        bs1, bs2, bd1, bd2, out);
}

// Round 4
// 46.584 us; speedup vs baseline: 4.8227x; 1.1342x over previous
//
#include <hip/hip_runtime.h>
#include <hip/hip_bf16.h>

// MADPSNet fused: entire 4-layer expert-selected MLP in ONE kernel.
// Round 4: attack the latency-bound profile (MfmaUtil 11%, Occ 10%).
//  - 512 threads = 8 waves = 2 waves/SIMD (was 1 -> zero TLP)
//  - waves split COLUMNS only (1x8): B weights read exactly once per block
//    (keeps L2 weight traffic at the 230 MB / ~6.7 us floor)
//  - explicit register pipeline: B prefetched 2 k-steps ahead (3 bufs),
//    A 1 step ahead (2 bufs); all indices compile-time (full unroll)
//  - activations stay in LDS (96 KB), XOR-swizzled both sides
//  - agent = bid&7 -> one agent's ~900 KB weights resident per XCD L2

typedef __attribute__((ext_vector_type(8))) short bf16x8;
typedef __attribute__((ext_vector_type(4))) float f32x4;

__device__ __forceinline__ ushort f2b(float x) {
    __hip_bfloat16 h = __float2bfloat16(x);
    return *reinterpret_cast<ushort*>(&h);
}

// swizzled LDS byte offset for bf16 (row, col); row stride = K elems (16B-chunk XOR)
__device__ __forceinline__ int swz_off(int row, int col, int K) {
    const int chunk = col >> 3;
    const int phys  = chunk ^ (row & 7);
    return row * (K * 2) + (phys << 4) + ((col & 7) << 1);
}

// ------------------------------------------------------------------ prep ---
// W[e][K][N] fp32 -> Wt[e][N][K] bf16 for all 4 layers, one kernel.
__global__ __launch_bounds__(256)
void prep_weights(const float* __restrict__ Ws1, const float* __restrict__ Ws2,
                  const float* __restrict__ Wd1, const float* __restrict__ Wd2,
                  ushort* __restrict__ W1t, ushort* __restrict__ W2t,
                  ushort* __restrict__ W3t, ushort* __restrict__ W4t)
{
    int t = blockIdx.x;
    const int e = blockIdx.z;
    const float* W; ushort* Wt; int K, N;
    if (t < 128)      { W = Ws1; Wt = W1t; K = 256; N = 512; }
    else if (t < 256) { t -= 128; W = Ws2; Wt = W2t; K = 512; N = 256; }
    else if (t < 384) { t -= 256; W = Wd1; Wt = W3t; K = 256; N = 512; }
    else              { t -= 384; W = Wd2; Wt = W4t; K = 512; N = 128; }
    W  += (size_t)e * K * N;
    Wt += (size_t)e * K * N;
    const int tn = N / 32;
    const int n0 = (t % tn) * 32;
    const int k0 = (t / tn) * 32;

    __shared__ float tile[32][33];
    const int tx = threadIdx.x;   // 0..31
    const int ty = threadIdx.y;   // 0..7
    #pragma unroll
    for (int j = 0; j < 4; ++j)
        tile[ty + j * 8][tx] = W[(size_t)(k0 + ty + j * 8) * N + n0 + tx];
    __syncthreads();
    #pragma unroll
    for (int j = 0; j < 4; ++j) {
        const int n = ty + j * 8;
        Wt[(size_t)(n0 + n) * K + k0 + tx] = f2b(tile[tx][n]);
    }
}

// ----------------------------------------------------------- fused layer ---
// A: LDS [64][K] bf16 swizzled. B: global Wt [N][K] bf16 (expert-selected).
// Wave `wid` owns cols [wid*N/8, (wid+1)*N/8). F = N/128 col-frags.
template<int K, int N, int RELU>
__device__ __forceinline__ void layer_mlp(
    const ushort* __restrict__ Wt, const float* __restrict__ bias,
    const ushort* __restrict__ sIn, ushort* __restrict__ sOut,
    float* __restrict__ gOut, int wid, int lane)
{
    constexpr int F  = N / 128;          // col frags per wave
    constexpr int NK = K / 32;           // k-steps
    const int r15 = lane & 15, lh = lane >> 4;
    const int wcol = wid * (N / 8);

    // lane-invariant-per-frag B base: col = wcol + f*16 + r15, elem k0 + lh*8
    const ushort* bBase = Wt + (size_t)(wcol + r15) * K + lh * 8;

    f32x4 acc[4][F];
    #pragma unroll
    for (int m = 0; m < 4; ++m)
        #pragma unroll
        for (int f = 0; f < F; ++f)
            acc[m][f] = (f32x4){0.f, 0.f, 0.f, 0.f};

    bf16x8 a[2][4], b[3][F];

    auto loadA = [&](int buf, int k0) {
        #pragma unroll
        for (int m = 0; m < 4; ++m) {
            const int row  = m * 16 + r15;
            const int phys = ((k0 >> 3) + lh) ^ (row & 7);
            a[buf][m] = *reinterpret_cast<const bf16x8*>(
                reinterpret_cast<const char*>(sIn) + row * (K * 2) + (phys << 4));
        }
    };
    auto loadB = [&](int buf, int k0) {
        #pragma unroll
        for (int f = 0; f < F; ++f)
            b[buf][f] = *reinterpret_cast<const bf16x8*>(
                bBase + (size_t)f * 16 * K + k0);
    };

    // prologue: B 2 steps deep, A 1 step
    loadB(0, 0);
    if (NK > 1) loadB(1, 32);
    loadA(0, 0);

    #pragma unroll
    for (int s = 0; s < NK; ++s) {
        if (s + 2 < NK) loadB((s + 2) % 3, (s + 2) * 32);
        if (s + 1 < NK) loadA((s + 1) & 1, (s + 1) * 32);
        #pragma unroll
        for (int m = 0; m < 4; ++m)
            #pragma unroll
            for (int f = 0; f < F; ++f)
                acc[m][f] = __builtin_amdgcn_mfma_f32_16x16x32_bf16(
                    a[s & 1][m], b[s % 3][f], acc[m][f], 0, 0, 0);
    }

    // epilogue
    #pragma unroll
    for (int f = 0; f < F; ++f) {
        const int col = wcol + f * 16 + r15;
        const float bv = bias[col];
        #pragma unroll
        for (int m = 0; m < 4; ++m) {
            #pragma unroll
            for (int j = 0; j < 4; ++j) {
                const int row = m * 16 + lh * 4 + j;   // C/D layout (m89)
                float v = acc[m][f][j] + bv;
                if (RELU) v = fmaxf(v, 0.f);
                if (gOut) {
                    gOut[(size_t)row * N + col] = v;
                } else {
                    *reinterpret_cast<ushort*>(
                        reinterpret_cast<char*>(sOut) + swz_off(row, col, N)) = f2b(v);
                }
            }
        }
    }
}

// ----------------------------------------------------------- fused kernel ---
__global__ __launch_bounds__(512, 2)
void madps_fused(const float* __restrict__ X,
                 const int* __restrict__ sel_s, const int* __restrict__ sel_d,
                 const ushort* __restrict__ W1t, const ushort* __restrict__ W2t,
                 const ushort* __restrict__ W3t, const ushort* __restrict__ W4t,
                 const float* __restrict__ bs1, const float* __restrict__ bs2,
                 const float* __restrict__ bd1, const float* __restrict__ bd2,
                 float* __restrict__ out)
{
    constexpr int S = 256, H1 = 512, H2 = 256, D1 = 512, D2 = 128;

    __shared__ __align__(16) ushort buf0[64 * 256];   // 32 KB: X, then sh
    __shared__ __align__(16) ushort buf1[64 * 512];   // 64 KB: h, then d

    const int bid   = blockIdx.x;
    const int agent = bid & 7;          // agent == XCD -> weights L2-resident
    const int rb    = bid >> 3;         // row-block within agent (0..31)
    const int tid   = threadIdx.x;
    const int lane  = tid & 63;
    const int wid   = tid >> 6;         // 0..7

    const long long es = sel_s[agent];
    const long long ed = sel_d[agent];

    const float* Xa = X + ((size_t)agent * 2048 + (size_t)rb * 64) * S;

    // ---- stage X [64][256] fp32 -> buf0 bf16 (swizzled) ----
    #pragma unroll
    for (int i = 0; i < 8; ++i) {
        const int flat4 = i * 512 + tid;        // float4 index, 64/row
        const int row = flat4 >> 6;
        const int c4  = flat4 & 63;
        const float4 v = reinterpret_cast<const float4*>(Xa)[flat4];
        ushort4 o;
        o.x = f2b(v.x); o.y = f2b(v.y); o.z = f2b(v.z); o.w = f2b(v.w);
        const int byteoff = (((c4 >> 1) ^ (row & 7)) << 4) | ((c4 & 1) << 3);
        *reinterpret_cast<ushort4*>(
            reinterpret_cast<char*>(buf0) + row * 512 + byteoff) = o;
    }
    __syncthreads();

    // L1: X(buf0, K=256) @ W1t -> relu -> h(buf1, N=512)
    layer_mlp<S, H1, 1>(W1t + es * (S * H1), bs1 + es * H1,
                        buf0, buf1, nullptr, wid, lane);
    __syncthreads();
    // L2: h(buf1, K=512) @ W2t -> relu -> sh(buf0, N=256)
    layer_mlp<H1, H2, 1>(W2t + es * (H1 * H2), bs2 + es * H2,
                         buf1, buf0, nullptr, wid, lane);
    __syncthreads();
    // L3: sh(buf0, K=256) @ W3t -> relu -> d(buf1, N=512)
    layer_mlp<H2, D1, 1>(W3t + ed * (H2 * D1), bd1 + ed * D1,
                         buf0, buf1, nullptr, wid, lane);
    __syncthreads();
    // L4: d(buf1, K=512) @ W4t + bias -> out fp32 [64][128]
    float* outP = out + ((size_t)agent * 2048 + (size_t)rb * 64) * D2;
    layer_mlp<D1, D2, 0>(W4t + ed * (D1 * D2), bd2 + ed * D2,
                         buf1, nullptr, outP, wid, lane);
}

// --------------------------------------------------------------- launch ---
extern "C" void kernel_launch(void* const* d_in, const int* in_sizes, int n_in,
                              void* d_out, int out_size, void* d_ws, size_t ws_size,
                              hipStream_t stream)
{
    constexpr int E = 8, S = 256, H1 = 512, H2 = 256, D1 = 512, D2 = 128;

    const float* inputs = (const float*)d_in[0];
    const int*   sel_s  = (const int*)d_in[1];
    const int*   sel_d  = (const int*)d_in[2];
    const float* Ws1 = (const float*)d_in[3];
    const float* bs1 = (const float*)d_in[4];
    const float* Ws2 = (const float*)d_in[5];
    const float* bs2 = (const float*)d_in[6];
    const float* Wd1 = (const float*)d_in[7];
    const float* bd1 = (const float*)d_in[8];
    const float* Wd2 = (const float*)d_in[9];
    const float* bd2 = (const float*)d_in[10];
    float* out = (float*)d_out;

    // workspace: transposed bf16 weights only
    ushort* W1t = (ushort*)d_ws;                     // [E][H1][S]
    ushort* W2t = W1t + (size_t)E * S * H1;          // [E][H2][H1]
    ushort* W3t = W2t + (size_t)E * H1 * H2;         // [E][D1][H2]
    ushort* W4t = W3t + (size_t)E * H2 * D1;         // [E][D2][D1]

    prep_weights<<<dim3(448, 1, E), dim3(32, 8), 0, stream>>>(
        Ws1, Ws2, Wd1, Wd2, W1t, W2t, W3t, W4t);

    madps_fused<<<dim3(256), dim3(512), 0, stream>>>(
        inputs, sel_s, sel_d, W1t, W2t, W3t, W4t,
        bs1, bs2, bd1, bd2, out);
}